// Round 16
// baseline (1149.176 us; speedup 1.0000x reference)
//
#include <hip/hip_runtime.h>
#include <hip/hip_bf16.h>

// ELMo 2-layer biLSTM, B=64 T=256 U=256. Persistent RNN, data-tagged sync.
//  R16 = R14 (618us, best) + 2-TICK-DEEP emb prefetch pipeline (single delta):
//   R14 issued ea ~500cy before its drain; embb (8MB) misses XCD L2 -> ~900cy
//   HBM latency -> per-WG tick-start stalls -> convoy jitter (consumer pays
//   max over 16 producers). Now ea for tick tau+2 issues at tick tau's tail:
//   a full tick (~5800cy) of slack. Two NAMED banks eaA/eaB + tick loop
//   unrolled x2 (compile-time bank index, rule #20).
//   Ledger: tick-start VMCNT(5) (real only at tick1; later ticks the prev
//   poll's VMCNT already drained the current bank); poll iter1 VMCNT(1) /
//   miss VMCNT(0) unchanged (other-bank loads are >=1 tick old).
//  LEDGER RULES: full-window poll ONLY (R7/R8/R13 hang); agent scope sc0 sc1
//  only (R12 livelock); coalesced ring stores (R11); 16-WG clusters (R15).

#define TT 256
#define TM 255
#define NU 256
#define NG 1024
#define BB 64

typedef __attribute__((ext_vector_type(8))) short short8;
typedef __attribute__((ext_vector_type(4))) float f32x4;
typedef __attribute__((ext_vector_type(4))) unsigned int u32x4;

__device__ __forceinline__ unsigned short f2bf(float v) {
  unsigned int x = __float_as_uint(v);
  return (unsigned short)((x + 0x7FFFu + ((x >> 16) & 1u)) >> 16);
}
__device__ __forceinline__ float sigm(float x) { return 1.f / (1.f + __expf(-x)); }
__device__ __forceinline__ float tanhp(float x) {
  x = fminf(fmaxf(x, -15.f), 15.f);
  float e = __expf(-2.f * x);
  return (1.f - e) / (1.f + e);
}
#define VMCNT(n) asm volatile("s_waitcnt vmcnt(" #n ")" ::: "memory")
#define LGKM0() asm volatile("s_waitcnt lgkmcnt(0)" ::: "memory")
#define SCHEDBAR() __builtin_amdgcn_sched_barrier(0)
#define BAR() __builtin_amdgcn_s_barrier()

#define LLC_LOAD16(dst, ptr) \
  asm volatile("global_load_dwordx4 %0, %1, off sc0 sc1" : "=&v"(dst) : "v"(ptr) : "memory")
#define CACH_LOAD16(dst, ptr) \
  asm volatile("global_load_dwordx4 %0, %1, off" : "=&v"(dst) : "v"(ptr) : "memory")
#define STORE4(ptr, val) \
  asm volatile("global_store_dword %0, %1, off" :: "v"(ptr), "v"(val) : "memory")

__global__ void embed_kernel(const int* __restrict__ seqs, const float* __restrict__ E,
                             unsigned short* __restrict__ embb, float* __restrict__ out) {
  int b = blockIdx.x, t = blockIdx.y, d = threadIdx.x;
  int s = seqs[b * TT + t];
  float v = E[(size_t)s * NU + d];
  embb[((size_t)(b * TT + t)) * NU + d] = f2bf(v);
  if (t < TM) out[(((size_t)(0 * BB + b)) * TM + t) * NU + d] = v;
  if (t >= 1) out[(((size_t)(3 * BB + b)) * TM + (t - 1)) * NU + d] = v;
}

__launch_bounds__(512, 1)
__global__ void lstm_kernel(const int* __restrict__ seqs,
                            const float* __restrict__ Wf, const float* __restrict__ Uf,
                            const float* __restrict__ bf,
                            const float* __restrict__ Wb, const float* __restrict__ Ub,
                            const float* __restrict__ bb,
                            const unsigned short* __restrict__ embb,
                            unsigned int* __restrict__ Hbuf, float* __restrict__ out) {
  extern __shared__ char smem[];
  float* zpart = (float*)smem;                    // [2][4][2][16][16] f32 = 16KB
  char* hlb0 = smem + 16384;                      // 8KB swizzled h0 tile
  char* hlb1 = smem + 24576;                      // 8KB swizzled h1 tile
  unsigned char* mskl = (unsigned char*)(smem + 32768);  // [64][256] = 16KB

  const int tid = threadIdx.x;
  const int blk = blockIdx.x;
  const int cluster = blk & 7, slice = blk >> 3;  // cluster -> same XCD (perf only)
  const int dir = cluster >> 2, rg = cluster & 3;
  const int ubase = slice << 4;
  const int wave = tid >> 6, g = wave & 3, kh = wave >> 2;
  const int lane = tid & 63, q = lane >> 4, n15 = lane & 15;
  const int tlay = tid >> 8, ct = tid & 255, crow = ct >> 4, cn = ct & 15;
  const int brow = rg * 16 + crow;

  const float* W0 = dir ? Wb : Wf;
  const float* U0 = dir ? Ub : Uf;
  const float* b0p = dir ? bb : bf;
  const float* mats[4] = {W0, U0, W0 + NU * NG, U0 + NU * NG};

  // ---- weights -> VGPRs
  short8 wreg[16];
  {
    const int col = g * 256 + ubase + n15;
    #pragma unroll
    for (int m = 0; m < 4; m++) {
      #pragma unroll
      for (int kb = 0; kb < 4; kb++) {
        short8 t;
        #pragma unroll
        for (int j = 0; j < 8; j++)
          t[j] = (short)f2bf(mats[m][(size_t)(kh * 128 + kb * 32 + q * 8 + j) * NG + col]);
        wreg[m * 4 + kb] = t;
      }
    }
  }

  // ---- mask table (LDS)
  for (int i = tid; i < 64 * 256; i += 512) {
    int row = i >> 8, s = i & 255;
    mskl[i] = (s < TM) ? (seqs[row * TT + (dir ? TM - s : s)] != 0) : 0;
  }

  float bi[4];
  {
    const float* bp = tlay ? (b0p + NG) : b0p;
    #pragma unroll
    for (int gg = 0; gg < 4; gg++) bi[gg] = bp[(gg << 8) + ubase + cn];
  }
  float cst = 0.f, hv = 0.f;

  __syncthreads();

  const int wsw = (tid * 16) ^ (((tid >> 5) & 7) << 4);
  const int fb = n15 * 512 + kh * 256;
  const int fx = (n15 & 7) << 4;
  const int zwr = (g << 9) + (kh << 8) + n15;

  unsigned int* hst = Hbuf + ((size_t)(tlay * 16 + cluster)) * 4096 + crow * 256 + ubase + cn;
  float* dump = (float*)((char*)Hbuf + 524288) + (blk * 512 + tid);

  const float* pendA = dump;
  float pendV = 0.f;
  bool havePend = false;

  short8 eaA[4], eaB[4];  // 2-deep emb pipeline: even ticks use A, odd use B
  const unsigned short* embase = embb + ((size_t)((rg * 16 + n15) * TT)) * NU + kh * 128 + q * 8;

  // ================= tick 0: emb-only, L0 combine =================
  {
    int tx = dir ? TM : 0;
    const unsigned short* ep = embase + (size_t)tx * NU;
    f32x4 acc0 = {0.f, 0.f, 0.f, 0.f};
    #pragma unroll
    for (int kb = 0; kb < 4; kb++) {
      short8 a = *(const short8*)(ep + kb * 32);
      acc0 = __builtin_amdgcn_mfma_f32_16x16x32_bf16(a, wreg[kb], acc0, 0, 0, 0);
    }
    #pragma unroll
    for (int j = 0; j < 4; j++) zpart[zwr + (((q << 2) + j) << 4)] = acc0[j];
    LGKM0(); SCHEDBAR(); BAR();
    if (tlay == 0) {
      float z[4];
      #pragma unroll
      for (int gg = 0; gg < 4; gg++)
        z[gg] = zpart[(gg * 2) * 256 + crow * 16 + cn] +
                zpart[(gg * 2 + 1) * 256 + crow * 16 + cn] + bi[gg];
      float cnw = sigm(z[1]) * cst + sigm(z[0]) * tanhp(z[2]);
      float hnw = sigm(z[3]) * tanhp(cnw);
      if (mskl[brow * 256 + 0]) { cst = cnw; hv = hnw; }
      int tout = dir ? TM - 1 : 0;
      pendA = out + (((size_t)((1 + dir * 3) * BB + brow)) * TM + tout) * NU + ubase + cn;
      pendV = hv;
    }
    havePend = true;  // tlay1: dummy (dump) — balances the vmcnt ledger
    // prefetch ea for tick1 (bank B) then tick2 (bank A); BEFORE ring store
    {
      int t1 = dir ? TM - 1 : 1;
      int t2 = dir ? TM - 2 : 2;
      const unsigned short* e1 = embase + (size_t)t1 * NU;
      const unsigned short* e2 = embase + (size_t)t2 * NU;
      #pragma unroll
      for (int kb = 0; kb < 4; kb++) CACH_LOAD16(eaB[kb], e1 + kb * 32);
      #pragma unroll
      for (int kb = 0; kb < 4; kb++) CACH_LOAD16(eaA[kb], e2 + kb * 32);
    }
    SCHEDBAR();
    __hip_atomic_store(hst, (1u << 16) | (unsigned)f2bf(hv),
                       __ATOMIC_RELAXED, __HIP_MEMORY_SCOPE_AGENT);
  }

  // ---- tick body; eac = bank consumed THIS tick and refilled for tau+2
  auto tick = [&](int tau, short8 (&eac)[4]) {
    const bool doL0 = (tau < TM);
    const bool doH1 = (tau >= 2);
    const int step = tlay ? tau - 1 : tau;

    // tick start: at tick1 drains eaB (5 younger ops: eaA4 + rs); later ticks
    // the previous poll's VMCNT already drained eac -> effectively free.
    VMCNT(5); SCHEDBAR();

    f32x4 acc0 = {0.f, 0.f, 0.f, 0.f}, acc1 = {0.f, 0.f, 0.f, 0.f};
    if (doL0) {
      #pragma unroll
      for (int kb = 0; kb < 4; kb++)
        acc0 = __builtin_amdgcn_mfma_f32_16x16x32_bf16(eac[kb], wreg[kb], acc0, 0, 0, 0);
      SCHEDBAR();
    }

    // ---- poll tagged h words (FULL window; R14-exact shape)
    const unsigned tg = (unsigned)tau;
    const int p = (tau + 1) & 1;
    const unsigned int* c0a = Hbuf + ((size_t)(p * 8 + cluster)) * 4096 + tid * 8;
    const unsigned int* c0b = c0a + 4;
    const unsigned int* c1a = Hbuf + ((size_t)((2 + p) * 8 + cluster)) * 4096 + tid * 8;
    const unsigned int* c1b = c1a + 4;
    u32x4 a0 = {0, 0, 0, 0}, a1 = {0, 0, 0, 0}, b0v = {0, 0, 0, 0}, b1v = {0, 0, 0, 0};
    bool first = true;
    int miss = 0;
    for (;;) {
      LLC_LOAD16(a0, c0a);
      LLC_LOAD16(a1, c0b);
      if (doH1) { LLC_LOAD16(b0v, c1a); LLC_LOAD16(b1v, c1b); }
      if (first) {
        if (havePend) { STORE4(pendA, pendV); havePend = false; }
        first = false;
        VMCNT(1);
      } else {
        VMCNT(0);
      }
      SCHEDBAR();
      bool ok = (a0[0] >> 16) == tg && (a0[1] >> 16) == tg && (a0[2] >> 16) == tg &&
                (a0[3] >> 16) == tg && (a1[0] >> 16) == tg && (a1[1] >> 16) == tg &&
                (a1[2] >> 16) == tg && (a1[3] >> 16) == tg;
      if (doH1)
        ok = ok && (b0v[0] >> 16) == tg && (b0v[1] >> 16) == tg && (b0v[2] >> 16) == tg &&
             (b0v[3] >> 16) == tg && (b1v[0] >> 16) == tg && (b1v[1] >> 16) == tg &&
             (b1v[2] >> 16) == tg && (b1v[3] >> 16) == tg;
      if (__all(ok)) break;
      if (++miss > 2) __builtin_amdgcn_s_sleep(1);
    }
    // strip tags -> packed bf16, stage to swizzled LDS
    u32x4 s0, s1;
    s0[0] = (a0[0] & 0xFFFFu) | (a0[1] << 16);
    s0[1] = (a0[2] & 0xFFFFu) | (a0[3] << 16);
    s0[2] = (a1[0] & 0xFFFFu) | (a1[1] << 16);
    s0[3] = (a1[2] & 0xFFFFu) | (a1[3] << 16);
    *(u32x4*)(hlb0 + wsw) = s0;
    if (doH1) {
      s1[0] = (b0v[0] & 0xFFFFu) | (b0v[1] << 16);
      s1[1] = (b0v[2] & 0xFFFFu) | (b0v[3] << 16);
      s1[2] = (b1v[0] & 0xFFFFu) | (b1v[1] << 16);
      s1[3] = (b1v[2] & 0xFFFFu) | (b1v[3] << 16);
      *(u32x4*)(hlb1 + wsw) = s1;
    }
    LGKM0(); SCHEDBAR(); BAR();

    // ---- h MFMAs (A from LDS, B from wreg)
    #pragma unroll
    for (int kb = 0; kb < 4; kb++) {
      short8 h0f = *(const short8*)(hlb0 + ((fb + kb * 64 + q * 16) ^ fx));
      if (doL0) acc0 = __builtin_amdgcn_mfma_f32_16x16x32_bf16(h0f, wreg[4 + kb], acc0, 0, 0, 0);
      acc1 = __builtin_amdgcn_mfma_f32_16x16x32_bf16(h0f, wreg[8 + kb], acc1, 0, 0, 0);
    }
    if (doH1) {
      #pragma unroll
      for (int kb = 0; kb < 4; kb++) {
        short8 h1f = *(const short8*)(hlb1 + ((fb + kb * 64 + q * 16) ^ fx));
        acc1 = __builtin_amdgcn_mfma_f32_16x16x32_bf16(h1f, wreg[12 + kb], acc1, 0, 0, 0);
      }
    }

    // ---- z partials
    if (doL0) {
      #pragma unroll
      for (int j = 0; j < 4; j++) zpart[zwr + (((q << 2) + j) << 4)] = acc0[j];
    }
    #pragma unroll
    for (int j = 0; j < 4; j++) zpart[2048 + zwr + (((q << 2) + j) << 4)] = acc1[j];
    LGKM0(); SCHEDBAR(); BAR();

    // ---- refill eac with emb for tick tau+2 (full tick of slack)
    {
      int tnext = tau + 2;
      if (tnext < TM) {
        int tx1 = dir ? TM - tnext : tnext;
        const unsigned short* e1 = embase + (size_t)tx1 * NU;
        #pragma unroll
        for (int kb = 0; kb < 4; kb++) CACH_LOAD16(eac[kb], e1 + kb * 32);
      }
    }
    SCHEDBAR();

    // ---- combine (L0: threads 0-255 @ step tau; L1: threads 256-511 @ tau-1)
    if (tlay ? true : doL0) {
      float z[4];
      #pragma unroll
      for (int gg = 0; gg < 4; gg++)
        z[gg] = zpart[(tlay * 8 + gg * 2) * 256 + crow * 16 + cn] +
                zpart[(tlay * 8 + gg * 2 + 1) * 256 + crow * 16 + cn] + bi[gg];
      float cnw = sigm(z[1]) * cst + sigm(z[0]) * tanhp(z[2]);
      float hnw = sigm(z[3]) * tanhp(cnw);
      if (mskl[brow * 256 + step]) { cst = cnw; hv = hnw; }
      __hip_atomic_store(hst + (size_t)(tau & 1) * 32768,
                         ((unsigned)(tau + 1) << 16) | (unsigned)f2bf(hv),
                         __ATOMIC_RELAXED, __HIP_MEMORY_SCOPE_AGENT);
      int tout = dir ? TM - 1 - step : step;
      pendA = out + (((size_t)((1 + tlay + dir * 3) * BB + brow)) * TM + tout) * NU + ubase + cn;
      pendV = hv;
      havePend = true;
    }
  };

  // ================= ticks 1..255 (unrolled x2: odd=B, even=A) =================
  for (int tau = 1; tau < 256; tau += 2) {
    tick(tau, eaB);
    if (tau + 1 < 256) tick(tau + 1, eaA);
  }

  // flush the last deferred store (tlay1's step 254)
  if (havePend) STORE4(pendA, pendV);
}

extern "C" void kernel_launch(void* const* d_in, const int* in_sizes, int n_in,
                              void* d_out, int out_size, void* d_ws, size_t ws_size,
                              hipStream_t stream) {
  const int* seqs = (const int*)d_in[0];
  const float* E = (const float*)d_in[1];
  const float* Wf = (const float*)d_in[2];
  const float* Uf = (const float*)d_in[3];
  const float* bfp = (const float*)d_in[4];
  const float* Wb = (const float*)d_in[5];
  const float* Ub = (const float*)d_in[6];
  const float* bbp = (const float*)d_in[7];
  float* out = (float*)d_out;

  char* ws = (char*)d_ws;
  unsigned int* Hbuf = (unsigned int*)ws;                 // 512KB ring + 256KB dump
  unsigned short* embb = (unsigned short*)(ws + 1048576); // 8MB bf16 emb

  hipMemsetAsync(Hbuf, 0, 4 * 8 * 4096 * sizeof(unsigned int), stream);

  hipLaunchKernelGGL(embed_kernel, dim3(BB, TT), dim3(256), 0, stream,
                     seqs, E, embb, out);

  int smem = 49152;  // 16K zpart + 2x8K h tiles + 16K mask
  hipFuncSetAttribute(reinterpret_cast<const void*>(lstm_kernel),
                      hipFuncAttributeMaxDynamicSharedMemorySize, smem);
  hipLaunchKernelGGL(lstm_kernel, dim3(128), dim3(512), smem, stream,
                     seqs, Wf, Uf, bfp, Wb, Ub, bbp, embb, Hbuf, out);
}

// Round 17
// 804.832 us; speedup vs baseline: 1.4278x; 1.4278x over previous
//
#include <hip/hip_runtime.h>
#include <hip/hip_bf16.h>

// ELMo 2-layer biLSTM, B=64 T=256 U=256. Persistent RNN, data-tagged sync.
//  R17 = R14 protocol + R11's z^T lane-local combine + COALESCED stores via
//  f32 LDS h-bounce (fixes R11's scattered-store poison):
//   - mfma(A=weight, B=x/h): lane (q,n15) acc[j] = gate j of cell
//     (row n15, unit tile*4+q) -> combine fully in-register (zpart deleted).
//   - h bounced through padded LDS [2][16][17] f32 (2.2KB); ring/out stores
//     issued by the R14 combine-thread mapping -> 16-word coalesced runs,
//     out keeps f32 precision.
//   - Waves: role=wave>>2 (L0/L1), tile=wave&3 (4 units), full K=256/wave.
//   - Poll / ledger / 1-tick ea pipeline / barriers(2): R14-verbatim.
//  LEDGER RULES: full-window poll ONLY (R7/R8/R13 hang); agent scope sc0 sc1
//  (R12); coalesced ring stores (R11); 16-WG clusters (R15); nothing young+
//  slow older than poll loads (R16).

#define TT 256
#define TM 255
#define NU 256
#define NG 1024
#define BB 64

typedef __attribute__((ext_vector_type(8))) short short8;
typedef __attribute__((ext_vector_type(4))) float f32x4;
typedef __attribute__((ext_vector_type(4))) unsigned int u32x4;

__device__ __forceinline__ unsigned short f2bf(float v) {
  unsigned int x = __float_as_uint(v);
  return (unsigned short)((x + 0x7FFFu + ((x >> 16) & 1u)) >> 16);
}
__device__ __forceinline__ float sigm(float x) { return 1.f / (1.f + __expf(-x)); }
__device__ __forceinline__ float tanhp(float x) {
  x = fminf(fmaxf(x, -15.f), 15.f);
  float e = __expf(-2.f * x);
  return (1.f - e) / (1.f + e);
}
#define VMCNT(n) asm volatile("s_waitcnt vmcnt(" #n ")" ::: "memory")
#define LGKM0() asm volatile("s_waitcnt lgkmcnt(0)" ::: "memory")
#define SCHEDBAR() __builtin_amdgcn_sched_barrier(0)
#define BAR() __builtin_amdgcn_s_barrier()

#define LLC_LOAD16(dst, ptr) \
  asm volatile("global_load_dwordx4 %0, %1, off sc0 sc1" : "=&v"(dst) : "v"(ptr) : "memory")
#define CACH_LOAD16(dst, ptr) \
  asm volatile("global_load_dwordx4 %0, %1, off" : "=&v"(dst) : "v"(ptr) : "memory")
#define STORE4(ptr, val) \
  asm volatile("global_store_dword %0, %1, off" :: "v"(ptr), "v"(val) : "memory")

__global__ void embed_kernel(const int* __restrict__ seqs, const float* __restrict__ E,
                             unsigned short* __restrict__ embb, float* __restrict__ out) {
  int b = blockIdx.x, t = blockIdx.y, d = threadIdx.x;
  int s = seqs[b * TT + t];
  float v = E[(size_t)s * NU + d];
  embb[((size_t)(b * TT + t)) * NU + d] = f2bf(v);
  if (t < TM) out[(((size_t)(0 * BB + b)) * TM + t) * NU + d] = v;
  if (t >= 1) out[(((size_t)(3 * BB + b)) * TM + (t - 1)) * NU + d] = v;
}

__launch_bounds__(512, 1)
__global__ void lstm_kernel(const int* __restrict__ seqs,
                            const float* __restrict__ Wf, const float* __restrict__ Uf,
                            const float* __restrict__ bf,
                            const float* __restrict__ Wb, const float* __restrict__ Ub,
                            const float* __restrict__ bb,
                            const unsigned short* __restrict__ embb,
                            unsigned int* __restrict__ Hbuf, float* __restrict__ out) {
  extern __shared__ char smem[];
  char* hlb0 = smem;                              // 8KB swizzled h0 tile
  char* hlb1 = smem + 8192;                       // 8KB swizzled h1 tile
  float* hbf = (float*)(smem + 16384);            // [2][16][17] f32 h-bounce (2.2KB)
  unsigned char* mskl = (unsigned char*)(smem + 18560);  // [64][256] = 16KB

  const int tid = threadIdx.x;
  const int blk = blockIdx.x;
  const int cluster = blk & 7, slice = blk >> 3;  // cluster -> same XCD (perf only)
  const int dir = cluster >> 2, rg = cluster & 3;
  const int ubase = slice << 4;
  const int wave = tid >> 6;
  const int role = wave >> 2;       // 0 = L0, 1 = L1
  const int tile = wave & 3;        // 4-unit col tile
  const int lane = tid & 63, q = lane >> 4, n15 = lane & 15;
  const int lrow = rg * 16 + n15;   // this lane's batch row (cell owner)
  const int unit = ubase + tile * 4 + q;
  const int tlay = tid >> 8, ct = tid & 255, crow = ct >> 4, cn = ct & 15;
  const int brow = rg * 16 + crow;  // combine/store thread's row

  const float* W0 = dir ? Wb : Wf;
  const float* U0 = dir ? Ub : Uf;
  const float* b0p = dir ? bb : bf;

  // ---- weights -> VGPRs as A-frags (z^T, R11-verified mapping):
  // A-row r=n15: gate=r&3, unit_in_tile=r>>2; k = kb*32 + q*8 + j.
  const float* mx = role ? (W0 + NU * NG) : W0;
  const float* mh = role ? (U0 + NU * NG) : U0;
  short8 wx[8], wh[8];
  {
    const int gcol = (n15 & 3) * 256 + ubase + tile * 4 + (n15 >> 2);
    #pragma unroll
    for (int kb = 0; kb < 8; kb++) {
      short8 tx_, th_;
      #pragma unroll
      for (int j = 0; j < 8; j++) {
        int k = kb * 32 + q * 8 + j;
        tx_[j] = (short)f2bf(mx[(size_t)k * NG + gcol]);
        th_[j] = (short)f2bf(mh[(size_t)k * NG + gcol]);
      }
      wx[kb] = tx_;
      wh[kb] = th_;
    }
  }

  // ---- mask table (LDS)
  for (int i = tid; i < 64 * 256; i += 512) {
    int row = i >> 8, s = i & 255;
    mskl[i] = (s < TM) ? (seqs[row * TT + (dir ? TM - s : s)] != 0) : 0;
  }

  // per-lane cell state + bias (gate order i,f,g,o = j)
  float bi[4];
  #pragma unroll
  for (int j = 0; j < 4; j++) bi[j] = (role ? (b0p + NG) : b0p)[j * 256 + unit];
  float cst = 0.f, hv = 0.f;

  __syncthreads();

  const int wsw = (tid * 16) ^ (((tid >> 5) & 7) << 4);
  const int fx = (n15 & 7) << 4;
  const int hbw = role * 272 + n15 * 17 + tile * 4 + q;  // bounce write (padded)
  const int hbr = tlay * 272 + crow * 17 + cn;           // bounce read

  // ring word slot (combine-thread mapping, coalesced): [lay][par][cluster][4096]
  unsigned int* hst = Hbuf + ((size_t)(tlay * 16 + cluster)) * 4096 + crow * 256 + ubase + cn;
  float* dump = (float*)((char*)Hbuf + 524288) + (blk * 512 + tid);

  const float* pendA = dump;
  float pendV = 0.f;
  bool havePend = false;

  short8 ea[8];  // emb B-frags for CURRENT tick (role0; prefetched prev tick)
  const unsigned short* embase = embb + ((size_t)(lrow * TT)) * NU + q * 8;

  // ================= tick 0: emb-only, L0 lane-local combine =================
  {
    if (role == 0) {
      int tx = dir ? TM : 0;
      const unsigned short* ep = embase + (size_t)tx * NU;
      f32x4 acc = {0.f, 0.f, 0.f, 0.f};
      #pragma unroll
      for (int kb = 0; kb < 8; kb++) {
        short8 a = *(const short8*)(ep + kb * 32);
        acc = __builtin_amdgcn_mfma_f32_16x16x32_bf16(wx[kb], a, acc, 0, 0, 0);
      }
      float cnw = sigm(acc[1] + bi[1]) * cst + sigm(acc[0] + bi[0]) * tanhp(acc[2] + bi[2]);
      float hnw = sigm(acc[3] + bi[3]) * tanhp(cnw);
      if (mskl[lrow * 256 + 0]) { cst = cnw; hv = hnw; }
      hbf[hbw] = hv;
    } else {
      hbf[hbw] = 0.f;  // h1 init
    }
    LGKM0(); SCHEDBAR(); BAR();
    float hb = hbf[hbr];
    LGKM0(); SCHEDBAR();
    if (tlay == 0) {
      int tout = dir ? TM - 1 : 0;
      pendA = out + (((size_t)((1 + dir * 3) * BB + brow)) * TM + tout) * NU + ubase + cn;
      pendV = hb;
    }
    havePend = true;  // tlay1: dummy (dump)
    if (role == 0) {  // ea prefetch for tick 1 (before ring store)
      int t1 = dir ? TM - 1 : 1;
      const unsigned short* e1 = embase + (size_t)t1 * NU;
      #pragma unroll
      for (int kb = 0; kb < 8; kb++) CACH_LOAD16(ea[kb], e1 + kb * 32);
      SCHEDBAR();
    }
    __hip_atomic_store(hst, (1u << 16) | (unsigned)f2bf(hb),
                       __ATOMIC_RELAXED, __HIP_MEMORY_SCOPE_AGENT);
  }

  // ================= ticks 1..255 =================
  for (int tau = 1; tau < 256; ++tau) {
    const bool doL0 = (tau < TM);
    const bool doH1 = (tau >= 2);

    // tick start: role0 drains 8 ea loads (ring store may pend); role1 no-op
    VMCNT(1); SCHEDBAR();

    // pre-poll emb MFMAs (role0, pure reg)
    f32x4 accA = {0.f, 0.f, 0.f, 0.f};
    if (role == 0 && doL0) {
      #pragma unroll
      for (int kb = 0; kb < 8; kb++)
        accA = __builtin_amdgcn_mfma_f32_16x16x32_bf16(wx[kb], ea[kb], accA, 0, 0, 0);
      SCHEDBAR();
    }

    // ---- poll tagged h words (FULL window; R14-exact)
    const unsigned tg = (unsigned)tau;
    const int p = (tau + 1) & 1;
    const unsigned int* c0a = Hbuf + ((size_t)(p * 8 + cluster)) * 4096 + tid * 8;
    const unsigned int* c0b = c0a + 4;
    const unsigned int* c1a = Hbuf + ((size_t)((2 + p) * 8 + cluster)) * 4096 + tid * 8;
    const unsigned int* c1b = c1a + 4;
    u32x4 a0 = {0, 0, 0, 0}, a1 = {0, 0, 0, 0}, b0v = {0, 0, 0, 0}, b1v = {0, 0, 0, 0};
    bool first = true;
    int miss = 0;
    for (;;) {
      LLC_LOAD16(a0, c0a);
      LLC_LOAD16(a1, c0b);
      if (doH1) { LLC_LOAD16(b0v, c1a); LLC_LOAD16(b1v, c1b); }
      if (first) {
        if (havePend) { STORE4(pendA, pendV); havePend = false; }
        first = false;
        VMCNT(1);
      } else {
        VMCNT(0);
      }
      SCHEDBAR();
      bool ok = (a0[0] >> 16) == tg && (a0[1] >> 16) == tg && (a0[2] >> 16) == tg &&
                (a0[3] >> 16) == tg && (a1[0] >> 16) == tg && (a1[1] >> 16) == tg &&
                (a1[2] >> 16) == tg && (a1[3] >> 16) == tg;
      if (doH1)
        ok = ok && (b0v[0] >> 16) == tg && (b0v[1] >> 16) == tg && (b0v[2] >> 16) == tg &&
             (b0v[3] >> 16) == tg && (b1v[0] >> 16) == tg && (b1v[1] >> 16) == tg &&
             (b1v[2] >> 16) == tg && (b1v[3] >> 16) == tg;
      if (__all(ok)) break;
      if (++miss > 2) __builtin_amdgcn_s_sleep(1);
    }
    // strip tags -> packed bf16, stage to swizzled LDS
    u32x4 s0, s1;
    s0[0] = (a0[0] & 0xFFFFu) | (a0[1] << 16);
    s0[1] = (a0[2] & 0xFFFFu) | (a0[3] << 16);
    s0[2] = (a1[0] & 0xFFFFu) | (a1[1] << 16);
    s0[3] = (a1[2] & 0xFFFFu) | (a1[3] << 16);
    *(u32x4*)(hlb0 + wsw) = s0;
    if (doH1) {
      s1[0] = (b0v[0] & 0xFFFFu) | (b0v[1] << 16);
      s1[1] = (b0v[2] & 0xFFFFu) | (b0v[3] << 16);
      s1[2] = (b1v[0] & 0xFFFFu) | (b1v[1] << 16);
      s1[3] = (b1v[2] & 0xFFFFu) | (b1v[3] << 16);
      *(u32x4*)(hlb1 + wsw) = s1;
    }
    LGKM0(); SCHEDBAR(); BAR();

    // ---- h MFMAs (B = h frags from LDS [row n15][k]; A = wreg) + combine
    const bool act = role ? true : doL0;
    float hsv = hv;
    if (act) {
      f32x4 accB = {0.f, 0.f, 0.f, 0.f};
      if (role == 0) {  // h0 @ U0
        #pragma unroll
        for (int kb = 0; kb < 8; kb++) {
          short8 hf = *(const short8*)(hlb0 + ((n15 * 512 + kb * 64 + q * 16) ^ fx));
          accB = __builtin_amdgcn_mfma_f32_16x16x32_bf16(wh[kb], hf, accB, 0, 0, 0);
        }
      } else {  // h0 @ W1 (+ h1 @ U1)
        #pragma unroll
        for (int kb = 0; kb < 8; kb++) {
          short8 hf = *(const short8*)(hlb0 + ((n15 * 512 + kb * 64 + q * 16) ^ fx));
          accA = __builtin_amdgcn_mfma_f32_16x16x32_bf16(wx[kb], hf, accA, 0, 0, 0);
        }
        if (doH1) {
          #pragma unroll
          for (int kb = 0; kb < 8; kb++) {
            short8 hf = *(const short8*)(hlb1 + ((n15 * 512 + kb * 64 + q * 16) ^ fx));
            accB = __builtin_amdgcn_mfma_f32_16x16x32_bf16(wh[kb], hf, accB, 0, 0, 0);
          }
        }
      }
      const int step = role ? tau - 1 : tau;
      float cnw = sigm(accA[1] + accB[1] + bi[1]) * cst +
                  sigm(accA[0] + accB[0] + bi[0]) * tanhp(accA[2] + accB[2] + bi[2]);
      float hnw = sigm(accA[3] + accB[3] + bi[3]) * tanhp(cnw);
      if (mskl[lrow * 256 + step]) { cst = cnw; hv = hnw; }
      hsv = hv;
    }
    hbf[hbw] = hsv;  // lane-local h -> bounce (inactive lanes rewrite old val)
    LGKM0(); SCHEDBAR(); BAR();

    // ---- ea refill for tick tau+1 (role0; before ring store)
    if (role == 0 && tau < TM - 1) {
      int tx1 = dir ? TM - (tau + 1) : (tau + 1);
      const unsigned short* e1 = embase + (size_t)tx1 * NU;
      #pragma unroll
      for (int kb = 0; kb < 8; kb++) CACH_LOAD16(ea[kb], e1 + kb * 32);
      SCHEDBAR();
    }

    // ---- coalesced ring + deferred out stores (combine-thread mapping)
    {
      const int stepT = tlay ? tau - 1 : tau;
      const bool actT = tlay ? true : doL0;
      float hb = hbf[hbr];
      LGKM0(); SCHEDBAR();
      if (actT) {
        __hip_atomic_store(hst + (size_t)(tau & 1) * 32768,
                           ((unsigned)(tau + 1) << 16) | (unsigned)f2bf(hb),
                           __ATOMIC_RELAXED, __HIP_MEMORY_SCOPE_AGENT);
        int tout = dir ? TM - 1 - stepT : stepT;
        pendA = out + (((size_t)((1 + tlay + dir * 3) * BB + brow)) * TM + tout) * NU + ubase + cn;
        pendV = hb;
        havePend = true;
      }
    }
  }

  // flush the last deferred store (tlay1's step 254)
  if (havePend) STORE4(pendA, pendV);
}

extern "C" void kernel_launch(void* const* d_in, const int* in_sizes, int n_in,
                              void* d_out, int out_size, void* d_ws, size_t ws_size,
                              hipStream_t stream) {
  const int* seqs = (const int*)d_in[0];
  const float* E = (const float*)d_in[1];
  const float* Wf = (const float*)d_in[2];
  const float* Uf = (const float*)d_in[3];
  const float* bfp = (const float*)d_in[4];
  const float* Wb = (const float*)d_in[5];
  const float* Ub = (const float*)d_in[6];
  const float* bbp = (const float*)d_in[7];
  float* out = (float*)d_out;

  char* ws = (char*)d_ws;
  unsigned int* Hbuf = (unsigned int*)ws;                 // 512KB ring + 256KB dump
  unsigned short* embb = (unsigned short*)(ws + 1048576); // 8MB bf16 emb

  hipMemsetAsync(Hbuf, 0, 4 * 8 * 4096 * sizeof(unsigned int), stream);

  hipLaunchKernelGGL(embed_kernel, dim3(BB, TT), dim3(256), 0, stream,
                     seqs, E, embb, out);

  int smem = 34944;  // 2x8K h tiles + 2.2K bounce + 16K mask
  hipFuncSetAttribute(reinterpret_cast<const void*>(lstm_kernel),
                      hipFuncAttributeMaxDynamicSharedMemorySize, smem);
  hipLaunchKernelGGL(lstm_kernel, dim3(128), dim3(512), smem, stream,
                     seqs, Wf, Uf, bfp, Wb, Ub, bbp, embb, Hbuf, out);
}

// Round 18
// 617.974 us; speedup vs baseline: 1.8596x; 1.3024x over previous
//
#include <hip/hip_runtime.h>
#include <hip/hip_bf16.h>

// ELMo 2-layer biLSTM, B=64 T=256 U=256. Persistent RNN, data-tagged sync.
//  R18 = R14 (618us, best) + EXEC-MASKED RE-POLL (single delta):
//   Per-lane convergence in the poll loop: once a lane's FULL 64B window
//   verifies (all tags == tau), it stops re-loading (divergent if(!ok) ->
//   loads issue exec-masked for stragglers only). Round-2+ poll traffic
//   drops to the straggler fraction -> chip-wide LLC queueing relief.
//   NOT the banned sentinel pattern: every checking lane loads its full
//   window; passed lanes hold immutable tag-tau data (R10 stale-tolerance).
//  LEDGER RULES: full-window-per-checking-lane poll (R7/R8/R13 hang on
//  partial windows); agent scope sc0 sc1 only (R12); coalesced ring stores
//  (R11); 16-WG clusters (R15); nothing young+slow older than poll loads
//  (R16); no serial cross-lane hops in the tick (R17).

#define TT 256
#define TM 255
#define NU 256
#define NG 1024
#define BB 64

typedef __attribute__((ext_vector_type(8))) short short8;
typedef __attribute__((ext_vector_type(4))) float f32x4;
typedef __attribute__((ext_vector_type(4))) unsigned int u32x4;

__device__ __forceinline__ unsigned short f2bf(float v) {
  unsigned int x = __float_as_uint(v);
  return (unsigned short)((x + 0x7FFFu + ((x >> 16) & 1u)) >> 16);
}
__device__ __forceinline__ float sigm(float x) { return 1.f / (1.f + __expf(-x)); }
__device__ __forceinline__ float tanhp(float x) {
  x = fminf(fmaxf(x, -15.f), 15.f);
  float e = __expf(-2.f * x);
  return (1.f - e) / (1.f + e);
}
#define VMCNT(n) asm volatile("s_waitcnt vmcnt(" #n ")" ::: "memory")
#define LGKM0() asm volatile("s_waitcnt lgkmcnt(0)" ::: "memory")
#define SCHEDBAR() __builtin_amdgcn_sched_barrier(0)
#define BAR() __builtin_amdgcn_s_barrier()

#define LLC_LOAD16(dst, ptr) \
  asm volatile("global_load_dwordx4 %0, %1, off sc0 sc1" : "=&v"(dst) : "v"(ptr) : "memory")
#define CACH_LOAD16(dst, ptr) \
  asm volatile("global_load_dwordx4 %0, %1, off" : "=&v"(dst) : "v"(ptr) : "memory")
#define STORE4(ptr, val) \
  asm volatile("global_store_dword %0, %1, off" :: "v"(ptr), "v"(val) : "memory")

__global__ void embed_kernel(const int* __restrict__ seqs, const float* __restrict__ E,
                             unsigned short* __restrict__ embb, float* __restrict__ out) {
  int b = blockIdx.x, t = blockIdx.y, d = threadIdx.x;
  int s = seqs[b * TT + t];
  float v = E[(size_t)s * NU + d];
  embb[((size_t)(b * TT + t)) * NU + d] = f2bf(v);
  if (t < TM) out[(((size_t)(0 * BB + b)) * TM + t) * NU + d] = v;
  if (t >= 1) out[(((size_t)(3 * BB + b)) * TM + (t - 1)) * NU + d] = v;
}

__launch_bounds__(512, 1)
__global__ void lstm_kernel(const int* __restrict__ seqs,
                            const float* __restrict__ Wf, const float* __restrict__ Uf,
                            const float* __restrict__ bf,
                            const float* __restrict__ Wb, const float* __restrict__ Ub,
                            const float* __restrict__ bb,
                            const unsigned short* __restrict__ embb,
                            unsigned int* __restrict__ Hbuf, float* __restrict__ out) {
  extern __shared__ char smem[];
  float* zpart = (float*)smem;                    // [2][4][2][16][16] f32 = 16KB
  char* hlb0 = smem + 16384;                      // 8KB swizzled h0 tile
  char* hlb1 = smem + 24576;                      // 8KB swizzled h1 tile
  unsigned char* mskl = (unsigned char*)(smem + 32768);  // [64][256] = 16KB

  const int tid = threadIdx.x;
  const int blk = blockIdx.x;
  const int cluster = blk & 7, slice = blk >> 3;  // cluster -> same XCD (perf only)
  const int dir = cluster >> 2, rg = cluster & 3;
  const int ubase = slice << 4;
  const int wave = tid >> 6, g = wave & 3, kh = wave >> 2;
  const int lane = tid & 63, q = lane >> 4, n15 = lane & 15;
  const int tlay = tid >> 8, ct = tid & 255, crow = ct >> 4, cn = ct & 15;
  const int brow = rg * 16 + crow;

  const float* W0 = dir ? Wb : Wf;
  const float* U0 = dir ? Ub : Uf;
  const float* b0p = dir ? bb : bf;
  const float* mats[4] = {W0, U0, W0 + NU * NG, U0 + NU * NG};

  // ---- weights -> VGPRs: wreg[m*4+kb][j] = mat[kh*128+kb*32+q*8+j][g*256+ubase+n15]
  short8 wreg[16];
  {
    const int col = g * 256 + ubase + n15;
    #pragma unroll
    for (int m = 0; m < 4; m++) {
      #pragma unroll
      for (int kb = 0; kb < 4; kb++) {
        short8 t;
        #pragma unroll
        for (int j = 0; j < 8; j++)
          t[j] = (short)f2bf(mats[m][(size_t)(kh * 128 + kb * 32 + q * 8 + j) * NG + col]);
        wreg[m * 4 + kb] = t;
      }
    }
  }

  // ---- mask table (LDS)
  for (int i = tid; i < 64 * 256; i += 512) {
    int row = i >> 8, s = i & 255;
    mskl[i] = (s < TM) ? (seqs[row * TT + (dir ? TM - s : s)] != 0) : 0;
  }

  float bi[4];
  {
    const float* bp = tlay ? (b0p + NG) : b0p;
    #pragma unroll
    for (int gg = 0; gg < 4; gg++) bi[gg] = bp[(gg << 8) + ubase + cn];
  }
  float cst = 0.f, hv = 0.f;

  __syncthreads();

  const int wsw = (tid * 16) ^ (((tid >> 5) & 7) << 4);
  const int fb = n15 * 512 + kh * 256;
  const int fx = (n15 & 7) << 4;
  const int zwr = (g << 9) + (kh << 8) + n15;

  // ring word slot: [lay][parity][cluster][4096]
  unsigned int* hst = Hbuf + ((size_t)(tlay * 16 + cluster)) * 4096 + crow * 256 + ubase + cn;
  // dummy-pending scratch (ledger balancing for tlay1's first tick)
  float* dump = (float*)((char*)Hbuf + 524288) + (blk * 512 + tid);

  const float* pendA = dump;
  float pendV = 0.f;
  bool havePend = false;

  short8 ea[4];  // emb A-frags for the CURRENT tick (prefetched previous tick)

  // ================= tick 0: emb-only, L0 combine =================
  {
    int tx = dir ? TM : 0;
    const unsigned short* ep =
        embb + ((size_t)((rg * 16 + n15) * TT + tx)) * NU + kh * 128 + q * 8;
    f32x4 acc0 = {0.f, 0.f, 0.f, 0.f};
    #pragma unroll
    for (int kb = 0; kb < 4; kb++) {
      short8 a = *(const short8*)(ep + kb * 32);
      acc0 = __builtin_amdgcn_mfma_f32_16x16x32_bf16(a, wreg[kb], acc0, 0, 0, 0);
    }
    #pragma unroll
    for (int j = 0; j < 4; j++) zpart[zwr + (((q << 2) + j) << 4)] = acc0[j];
    LGKM0(); SCHEDBAR(); BAR();
    if (tlay == 0) {
      float z[4];
      #pragma unroll
      for (int gg = 0; gg < 4; gg++)
        z[gg] = zpart[(gg * 2) * 256 + crow * 16 + cn] +
                zpart[(gg * 2 + 1) * 256 + crow * 16 + cn] + bi[gg];
      float cnw = sigm(z[1]) * cst + sigm(z[0]) * tanhp(z[2]);
      float hnw = sigm(z[3]) * tanhp(cnw);
      if (mskl[brow * 256 + 0]) { cst = cnw; hv = hnw; }
      int tout = dir ? TM - 1 : 0;
      pendA = out + (((size_t)((1 + dir * 3) * BB + brow)) * TM + tout) * NU + ubase + cn;
      pendV = hv;
    }
    havePend = true;  // tlay1: dummy (dump) — balances the vmcnt ledger
    // emb prefetch for tick 1 (MUST precede ring store: tick-start VMCNT(1))
    {
      int tx1 = dir ? TM - 1 : 1;
      const unsigned short* e1 =
          embb + ((size_t)((rg * 16 + n15) * TT + tx1)) * NU + kh * 128 + q * 8;
      #pragma unroll
      for (int kb = 0; kb < 4; kb++) CACH_LOAD16(ea[kb], e1 + kb * 32);
    }
    SCHEDBAR();
    // ring store tag1 parity0
    __hip_atomic_store(hst, (1u << 16) | (unsigned)f2bf(hv),
                       __ATOMIC_RELAXED, __HIP_MEMORY_SCOPE_AGENT);
  }

  // ================= ticks 1..255 =================
  for (int tau = 1; tau < 256; ++tau) {
    const bool doL0 = (tau < TM);
    const bool doH1 = (tau >= 2);
    const int step = tlay ? tau - 1 : tau;

    // tick start: drain the 4 ea prefetch loads (oldest); ring store may pend
    VMCNT(1); SCHEDBAR();

    // pre-poll emb MFMAs (pure reg: ea x wreg)
    f32x4 acc0 = {0.f, 0.f, 0.f, 0.f}, acc1 = {0.f, 0.f, 0.f, 0.f};
    if (doL0) {
      #pragma unroll
      for (int kb = 0; kb < 4; kb++)
        acc0 = __builtin_amdgcn_mfma_f32_16x16x32_bf16(ea[kb], wreg[kb], acc0, 0, 0, 0);
      SCHEDBAR();
    }

    // ---- poll tagged h words: exec-masked re-poll (full window per lane)
    const unsigned tg = (unsigned)tau;
    const int p = (tau + 1) & 1;
    const unsigned int* c0a = Hbuf + ((size_t)(p * 8 + cluster)) * 4096 + tid * 8;
    const unsigned int* c0b = c0a + 4;
    const unsigned int* c1a = Hbuf + ((size_t)((2 + p) * 8 + cluster)) * 4096 + tid * 8;
    const unsigned int* c1b = c1a + 4;
    u32x4 a0 = {0, 0, 0, 0}, a1 = {0, 0, 0, 0}, b0v = {0, 0, 0, 0}, b1v = {0, 0, 0, 0};
    bool first = true;
    bool okl = false;  // per-lane: my full window verified
    int miss = 0;
    for (;;) {
      if (!okl) {  // stragglers only (exec-masked loads)
        LLC_LOAD16(a0, c0a);
        LLC_LOAD16(a1, c0b);
        if (doH1) { LLC_LOAD16(b0v, c1a); LLC_LOAD16(b1v, c1b); }
      }
      if (first) {
        if (havePend) { STORE4(pendA, pendV); havePend = false; }
        first = false;
        VMCNT(1);
      } else {
        VMCNT(0);
      }
      SCHEDBAR();
      if (!okl) {
        bool ok = (a0[0] >> 16) == tg && (a0[1] >> 16) == tg && (a0[2] >> 16) == tg &&
                  (a0[3] >> 16) == tg && (a1[0] >> 16) == tg && (a1[1] >> 16) == tg &&
                  (a1[2] >> 16) == tg && (a1[3] >> 16) == tg;
        if (doH1)
          ok = ok && (b0v[0] >> 16) == tg && (b0v[1] >> 16) == tg && (b0v[2] >> 16) == tg &&
               (b0v[3] >> 16) == tg && (b1v[0] >> 16) == tg && (b1v[1] >> 16) == tg &&
               (b1v[2] >> 16) == tg && (b1v[3] >> 16) == tg;
        okl = ok;
      }
      if (__all(okl)) break;
      if (++miss > 2) __builtin_amdgcn_s_sleep(1);
    }
    // strip tags -> packed bf16, stage to swizzled LDS
    u32x4 s0, s1;
    s0[0] = (a0[0] & 0xFFFFu) | (a0[1] << 16);
    s0[1] = (a0[2] & 0xFFFFu) | (a0[3] << 16);
    s0[2] = (a1[0] & 0xFFFFu) | (a1[1] << 16);
    s0[3] = (a1[2] & 0xFFFFu) | (a1[3] << 16);
    *(u32x4*)(hlb0 + wsw) = s0;
    if (doH1) {
      s1[0] = (b0v[0] & 0xFFFFu) | (b0v[1] << 16);
      s1[1] = (b0v[2] & 0xFFFFu) | (b0v[3] << 16);
      s1[2] = (b1v[0] & 0xFFFFu) | (b1v[1] << 16);
      s1[3] = (b1v[2] & 0xFFFFu) | (b1v[3] << 16);
      *(u32x4*)(hlb1 + wsw) = s1;
    }
    LGKM0(); SCHEDBAR(); BAR();

    // ---- h MFMAs (A from LDS, B from wreg)
    #pragma unroll
    for (int kb = 0; kb < 4; kb++) {
      short8 h0f = *(const short8*)(hlb0 + ((fb + kb * 64 + q * 16) ^ fx));
      if (doL0) acc0 = __builtin_amdgcn_mfma_f32_16x16x32_bf16(h0f, wreg[4 + kb], acc0, 0, 0, 0);
      acc1 = __builtin_amdgcn_mfma_f32_16x16x32_bf16(h0f, wreg[8 + kb], acc1, 0, 0, 0);
    }
    if (doH1) {
      #pragma unroll
      for (int kb = 0; kb < 4; kb++) {
        short8 h1f = *(const short8*)(hlb1 + ((fb + kb * 64 + q * 16) ^ fx));
        acc1 = __builtin_amdgcn_mfma_f32_16x16x32_bf16(h1f, wreg[12 + kb], acc1, 0, 0, 0);
      }
    }

    // ---- z partials
    if (doL0) {
      #pragma unroll
      for (int j = 0; j < 4; j++) zpart[zwr + (((q << 2) + j) << 4)] = acc0[j];
    }
    #pragma unroll
    for (int j = 0; j < 4; j++) zpart[2048 + zwr + (((q << 2) + j) << 4)] = acc1[j];
    LGKM0(); SCHEDBAR(); BAR();

    // ---- emb prefetch for tick tau+1 (before ring store; all threads)
    if (tau < TM - 1) {
      int tx1 = dir ? TM - (tau + 1) : (tau + 1);
      const unsigned short* e1 =
          embb + ((size_t)((rg * 16 + n15) * TT + tx1)) * NU + kh * 128 + q * 8;
      #pragma unroll
      for (int kb = 0; kb < 4; kb++) CACH_LOAD16(ea[kb], e1 + kb * 32);
    }
    SCHEDBAR();

    // ---- combine (L0: threads 0-255 @ step tau; L1: threads 256-511 @ tau-1)
    if (tlay ? true : doL0) {
      float z[4];
      #pragma unroll
      for (int gg = 0; gg < 4; gg++)
        z[gg] = zpart[(tlay * 8 + gg * 2) * 256 + crow * 16 + cn] +
                zpart[(tlay * 8 + gg * 2 + 1) * 256 + crow * 16 + cn] + bi[gg];
      float cnw = sigm(z[1]) * cst + sigm(z[0]) * tanhp(z[2]);
      float hnw = sigm(z[3]) * tanhp(cnw);
      if (mskl[brow * 256 + step]) { cst = cnw; hv = hnw; }
      // ring store: tag tau+1, parity tau&1, fire-and-forget sc1
      __hip_atomic_store(hst + (size_t)(tau & 1) * 32768,
                         ((unsigned)(tau + 1) << 16) | (unsigned)f2bf(hv),
                         __ATOMIC_RELAXED, __HIP_MEMORY_SCOPE_AGENT);
      // defer the fp32 out store to next tick's poll
      int tout = dir ? TM - 1 - step : step;
      pendA = out + (((size_t)((1 + tlay + dir * 3) * BB + brow)) * TM + tout) * NU + ubase + cn;
      pendV = hv;
      havePend = true;
    }
  }

  // flush the last deferred store (tlay1's step 254)
  if (havePend) STORE4(pendA, pendV);
}

extern "C" void kernel_launch(void* const* d_in, const int* in_sizes, int n_in,
                              void* d_out, int out_size, void* d_ws, size_t ws_size,
                              hipStream_t stream) {
  const int* seqs = (const int*)d_in[0];
  const float* E = (const float*)d_in[1];
  const float* Wf = (const float*)d_in[2];
  const float* Uf = (const float*)d_in[3];
  const float* bfp = (const float*)d_in[4];
  const float* Wb = (const float*)d_in[5];
  const float* Ub = (const float*)d_in[6];
  const float* bbp = (const float*)d_in[7];
  float* out = (float*)d_out;

  char* ws = (char*)d_ws;
  unsigned int* Hbuf = (unsigned int*)ws;                 // 512KB ring + 256KB dump
  unsigned short* embb = (unsigned short*)(ws + 1048576); // 8MB bf16 emb

  hipMemsetAsync(Hbuf, 0, 4 * 8 * 4096 * sizeof(unsigned int), stream);

  hipLaunchKernelGGL(embed_kernel, dim3(BB, TT), dim3(256), 0, stream,
                     seqs, E, embb, out);

  int smem = 49152;  // 16K zpart + 2x8K h tiles + 16K mask
  hipFuncSetAttribute(reinterpret_cast<const void*>(lstm_kernel),
                      hipFuncAttributeMaxDynamicSharedMemorySize, smem);
  hipLaunchKernelGGL(lstm_kernel, dim3(128), dim3(512), smem, stream,
                     seqs, Wf, Uf, bfp, Wb, Ub, bbp, embb, Hbuf, out);
}